// Round 4
// baseline (290.166 us; speedup 1.0000x reference)
//
#include <hip/hip_runtime.h>
#include <hip/hip_bf16.h>

#define T_TOK 8192
#define DH    1024
#define NE    8
#define TK    4

typedef unsigned short u16;
typedef __bf16 bf16x8 __attribute__((ext_vector_type(8)));
typedef float  f32x4  __attribute__((ext_vector_type(4)));

__device__ __forceinline__ u16 f2b(float f) {
    union { float f; unsigned u; } v; v.f = f;
    unsigned u = v.u;
    u += 0x7FFFu + ((u >> 16) & 1u);   // round-to-nearest-even
    return (u16)(u >> 16);
}
__device__ __forceinline__ float b2f(u16 h) {
    union { unsigned u; float f; } v; v.u = ((unsigned)h) << 16;
    return v.f;
}
// async global->LDS, 16B per lane; LDS dest = wave-uniform base + lane*16
__device__ __forceinline__ void glds16(const u16* g, u16* l) {
    __builtin_amdgcn_global_load_lds((const __attribute__((address_space(1))) void*)g,
                                     (__attribute__((address_space(3))) void*)l, 16, 0, 0);
}

// ---------------- cast W -> bf16, transposed to [e][f][d] ----------------
__global__ __launch_bounds__(256) void cast_w_kernel(const float* __restrict__ W,
                                                     u16* __restrict__ wbt) {
    __shared__ float tile[32][33];
    const int e  = blockIdx.z;
    const int d0 = blockIdx.y * 32;
    const int f0 = blockIdx.x * 32;
    const float* src = W + ((size_t)e << 20);
    for (int r = threadIdx.y; r < 32; r += 8)
        tile[r][threadIdx.x] = src[(size_t)(d0 + r) * DH + f0 + threadIdx.x];
    __syncthreads();
    u16* dst = wbt + ((size_t)e << 20);
    for (int r = threadIdx.y; r < 32; r += 8)
        dst[(size_t)(f0 + r) * DH + d0 + threadIdx.x] = f2b(tile[threadIdx.x][r]);
}

// ---------------- router: logits + softmax + top4 + buckets, fused x->bf16 cast ----------------
__global__ __launch_bounds__(512) void router_kernel(
    const float* __restrict__ x, const float* __restrict__ Wg, const float* __restrict__ bg,
    u16* __restrict__ xb,
    int* __restrict__ bucket_tok, float* __restrict__ bucket_w,
    int* __restrict__ tk_e, float* __restrict__ tk_w,
    int* __restrict__ cnt, float* __restrict__ probsum)
{
    __shared__ int   lcnt[NE];
    __shared__ float lprob[NE];
    __shared__ int   gbase[NE];
    const int tid = threadIdx.x;
    const int wv = tid >> 6, lane = tid & 63;
    const int t = blockIdx.x * 8 + wv;
    if (tid < NE) { lcnt[tid] = 0; lprob[tid] = 0.f; }
    __syncthreads();

    float a[NE] = {};
    {
        const float* xr = x + (size_t)t * DH;
        u16* xbr = xb + (size_t)t * DH;
        #pragma unroll
        for (int it = 0; it < 4; it++) {
            const int d = it * 256 + lane * 4;
            const float4 v = *(const float4*)(xr + d);
            ushort4 o;
            o.x = f2b(v.x); o.y = f2b(v.y); o.z = f2b(v.z); o.w = f2b(v.w);
            *(ushort4*)(xbr + d) = o;
            const float* wr = Wg + d * NE;
            #pragma unroll
            for (int e = 0; e < NE; e++)
                a[e] += v.x * wr[e] + v.y * wr[NE + e] + v.z * wr[2 * NE + e] + v.w * wr[3 * NE + e];
        }
    }
    #pragma unroll
    for (int e = 0; e < NE; e++) {
        float v = a[e];
        #pragma unroll
        for (int off = 32; off > 0; off >>= 1) v += __shfl_down(v, off);
        a[e] = v;
    }

    int idx4[TK]; float w4[TK]; int off4[TK];
    if (lane == 0) {
        float logits[NE], probs[NE];
        float mx = -1e30f;
        #pragma unroll
        for (int e = 0; e < NE; e++) { logits[e] = a[e] + bg[e]; mx = fmaxf(mx, logits[e]); }
        float Z = 0.f;
        #pragma unroll
        for (int e = 0; e < NE; e++) { probs[e] = expf(logits[e] - mx); Z += probs[e]; }
        const float rZ = 1.f / Z;
        #pragma unroll
        for (int e = 0; e < NE; e++) probs[e] *= rZ;

        float rem2[NE];
        #pragma unroll
        for (int e = 0; e < NE; e++) rem2[e] = probs[e];
        float s4 = 0.f;
        #pragma unroll
        for (int k = 0; k < TK; k++) {   // strict > scan from 0 == jax tie-break (lowest idx)
            int best = 0; float bv = rem2[0];
            #pragma unroll
            for (int e = 1; e < NE; e++) if (rem2[e] > bv) { bv = rem2[e]; best = e; }
            idx4[k] = best; w4[k] = bv; s4 += bv; rem2[best] = -1e30f;
        }
        const float rs = 1.f / (s4 + 1e-6f);
        #pragma unroll
        for (int k = 0; k < TK; k++) {
            w4[k] *= rs;
            tk_e[t * TK + k] = idx4[k];
            tk_w[t * TK + k] = w4[k];
            off4[k] = atomicAdd(&lcnt[idx4[k]], 1);
        }
        #pragma unroll
        for (int e = 0; e < NE; e++) atomicAdd(&lprob[e], probs[e]);
    }
    __syncthreads();
    if (tid < NE) {
        gbase[tid] = atomicAdd(&cnt[tid], lcnt[tid]);
        atomicAdd(&probsum[tid], lprob[tid]);
    }
    __syncthreads();
    if (lane == 0) {
        #pragma unroll
        for (int k = 0; k < TK; k++) {
            const int e = idx4[k];
            const int slot = gbase[e] + off4[k];
            bucket_tok[e * T_TOK + slot] = (t << 2) | k;
            bucket_w[e * T_TOK + slot]   = w4[k];
        }
    }
}

// ---------------- grouped gather GEMM: y[t*4+k] = w * (x[t] @ W[e]) ----------------
// BK=64: 32 MFMA per barrier (2x amortization of the vmcnt(0)+s_barrier drain),
// LDS 33.8 KB -> ~4 blocks/CU. global_load_lds width-16 staging, unpadded LDS.
__global__ __launch_bounds__(256) void moe_gemm_kernel(
    const u16* __restrict__ xb, const u16* __restrict__ wbt,
    const int* __restrict__ bucket_tok, const float* __restrict__ bucket_w,
    const int* __restrict__ cnt, u16* __restrict__ y)
{
    const int e  = blockIdx.z;
    const int M  = cnt[e];
    const int m0 = blockIdx.y * 128;
    if (m0 >= M) return;
    const int n0 = blockIdx.x * 128;

    __shared__ u16 As[128 * 64];   // 16 KB, unpadded (global_load_lds layout)
    __shared__ u16 Bs[128 * 64];   // 16 KB
    __shared__ int   s_tok[128];
    __shared__ float s_w[128];

    const int tid  = threadIdx.x;
    const int lane = tid & 63;
    const int wave = tid >> 6;

    if (tid < 128) {
        const int slot = m0 + tid;
        if (slot < M) {
            s_tok[tid] = bucket_tok[e * T_TOK + slot];
            s_w[tid]   = bucket_w[e * T_TOK + slot];
        } else { s_tok[tid] = -1; s_w[tid] = 0.f; }
    }
    __syncthreads();

    // staging: 16 segments of 8 rows x 128 B; wave w owns segs w*4..w*4+3.
    // lane l -> row seg*8 + l/8, u16 col (l&7)*8  (LDS dest = base + l*16 B).
    const int lr = lane >> 3;          // 0..7
    const int c8 = (lane & 7) * 8;     // 0,8,...,56
    const u16* gA[4];
    const u16* gB[4];
    u16* lA[4];
    u16* lB[4];
    const u16* wb_e = wbt + ((size_t)e << 20);
    #pragma unroll
    for (int j = 0; j < 4; j++) {
        const int seg = wave * 4 + j;
        const int row = seg * 8 + lr;
        const int tj  = s_tok[row];
        gA[j] = xb + (size_t)(tj >= 0 ? (tj >> 2) : 0) * DH + c8;
        gB[j] = wb_e + (size_t)(n0 + row) * DH + c8;
        lA[j] = &As[seg * 512];
        lB[j] = &Bs[seg * 512];
    }

    const int mrow = (wave >> 1) * 64;
    const int ncol = (wave & 1) * 64;
    const int fr   = lane & 15;
    const int fq   = (lane >> 4) * 8;

    f32x4 acc[4][4] = {};

    for (int k0 = 0; k0 < DH; k0 += 64) {
        #pragma unroll
        for (int j = 0; j < 4; j++) glds16(gA[j] + k0, lA[j]);
        #pragma unroll
        for (int j = 0; j < 4; j++) glds16(gB[j] + k0, lB[j]);
        __syncthreads();
        #pragma unroll
        for (int h = 0; h < 2; h++) {
            bf16x8 af[4], bfv[4];
            #pragma unroll
            for (int i = 0; i < 4; i++)
                af[i] = *(const bf16x8*)&As[(mrow + i * 16 + fr) * 64 + h * 32 + fq];
            #pragma unroll
            for (int j = 0; j < 4; j++)
                bfv[j] = *(const bf16x8*)&Bs[(ncol + j * 16 + fr) * 64 + h * 32 + fq];
            #pragma unroll
            for (int i = 0; i < 4; i++)
                #pragma unroll
                for (int j = 0; j < 4; j++)
                    acc[i][j] = __builtin_amdgcn_mfma_f32_16x16x32_bf16(af[i], bfv[j], acc[i][j], 0, 0, 0);
        }
        __syncthreads();
    }

    // C/D layout: col = lane&15, row = (lane>>4)*4 + r
    const int cl = lane & 15;
    const int rb = (lane >> 4) * 4;
    #pragma unroll
    for (int i = 0; i < 4; i++) {
        #pragma unroll
        for (int r = 0; r < 4; r++) {
            const int srow = mrow + i * 16 + rb + r;
            const int tok = s_tok[srow];
            if (tok < 0) continue;
            const float w = s_w[srow];
            u16* yr = y + (size_t)tok * DH + (n0 + ncol + cl);
            #pragma unroll
            for (int j = 0; j < 4; j++)
                yr[j * 16] = f2b(acc[i][j][r] * w);
        }
    }
}

// ---------------- combine: out[t] = sum_k y[t*4+k] + sum_k w_k*b[e_k]; block 0 does aux ----------------
__global__ __launch_bounds__(256) void combine_kernel(
    const u16* __restrict__ y, const int* __restrict__ tk_e, const float* __restrict__ tk_w,
    const float* __restrict__ bexp,
    const int* __restrict__ cnt, const float* __restrict__ probsum,
    float* __restrict__ out, float* __restrict__ out_aux)
{
    const int t = blockIdx.x;
    const int c = threadIdx.x * 4;
    if (t == 0 && threadIdx.x == 0) {
        float s = 0.f;
        for (int e = 0; e < NE; e++) s += (float)cnt[e] * probsum[e];
        out_aux[0] = s * (float)NE / ((float)T_TOK * (float)T_TOK);
    }
    float o0 = 0.f, o1 = 0.f, o2 = 0.f, o3 = 0.f;
    #pragma unroll
    for (int k = 0; k < TK; k++) {
        const int e   = tk_e[t * TK + k];
        const float w = tk_w[t * TK + k];
        const ushort4 yv = *(const ushort4*)(y + ((size_t)(t * TK + k)) * DH + c);
        const float4  bv = *(const float4*)(bexp + (size_t)e * DH + c);
        o0 += b2f(yv.x) + w * bv.x;
        o1 += b2f(yv.y) + w * bv.y;
        o2 += b2f(yv.z) + w * bv.z;
        o3 += b2f(yv.w) + w * bv.w;
    }
    float4 ov = {o0, o1, o2, o3};
    *(float4*)(out + (size_t)t * DH + c) = ov;
}

extern "C" void kernel_launch(void* const* d_in, const int* in_sizes, int n_in,
                              void* d_out, int out_size, void* d_ws, size_t ws_size,
                              hipStream_t stream)
{
    const float* x  = (const float*)d_in[0];
    const float* Wg = (const float*)d_in[1];
    const float* bg = (const float*)d_in[2];
    const float* W  = (const float*)d_in[3];
    const float* b  = (const float*)d_in[4];
    float* out = (float*)d_out;

    char* ws = (char*)d_ws;
    u16*   xb         = (u16*)(ws);                    // 16,777,216 B
    u16*   wbt        = (u16*)(ws + 16777216);         // 16,777,216 B
    u16*   y          = (u16*)(ws + 33554432);         // 67,108,864 B
    int*   bucket_tok = (int*)(ws + 100663296);        //    262,144 B
    float* bucket_w   = (float*)(ws + 100925440);      //    262,144 B
    int*   tk_e       = (int*)(ws + 101187584);        //    131,072 B
    float* tk_w       = (float*)(ws + 101318656);      //    131,072 B
    int*   cnt        = (int*)(ws + 101449728);        //         32 B
    float* probsum    = (float*)(ws + 101449760);      //         32 B

    hipMemsetAsync(cnt, 0, 64, stream);  // cnt + probsum

    cast_w_kernel<<<dim3(32, 32, NE), dim3(32, 8, 1), 0, stream>>>(W, wbt);
    router_kernel<<<1024, 512, 0, stream>>>(x, Wg, bg, xb, bucket_tok, bucket_w, tk_e, tk_w, cnt, probsum);
    moe_gemm_kernel<<<dim3(8, 64, NE), 256, 0, stream>>>(xb, wbt, bucket_tok, bucket_w, cnt, y);
    combine_kernel<<<8192, 256, 0, stream>>>(y, tk_e, tk_w, b, cnt, probsum, out, out + (size_t)T_TOK * DH);
}

// Round 5
// 257.514 us; speedup vs baseline: 1.1268x; 1.1268x over previous
//
#include <hip/hip_runtime.h>
#include <hip/hip_bf16.h>

#define T_TOK 8192
#define DH    1024
#define NE    8
#define TK    4

typedef unsigned short u16;
typedef __bf16 bf16x8 __attribute__((ext_vector_type(8)));
typedef float  f32x4  __attribute__((ext_vector_type(4)));

__device__ __forceinline__ u16 f2b(float f) {
    union { float f; unsigned u; } v; v.f = f;
    unsigned u = v.u;
    u += 0x7FFFu + ((u >> 16) & 1u);   // round-to-nearest-even
    return (u16)(u >> 16);
}
__device__ __forceinline__ float b2f(u16 h) {
    union { unsigned u; float f; } v; v.u = ((unsigned)h) << 16;
    return v.f;
}
// async global->LDS, 16B per lane; LDS dest = wave-uniform base + lane*16
__device__ __forceinline__ void glds16(const u16* g, u16* l) {
    __builtin_amdgcn_global_load_lds((const __attribute__((address_space(1))) void*)g,
                                     (__attribute__((address_space(3))) void*)l, 16, 0, 0);
}

// ---------------- cast W -> bf16, transposed to [e][f][d]; 64x64 tile, vectorized ----------------
// reads: float4 coalesced (16 lanes x 16B = 256B per row); writes: ushort4 coalesced.
// LDS tile[64][65]: column reads on the write side stride 65*4B -> banks step 4 mod 32 (2-way, free).
__global__ __launch_bounds__(256) void cast_w_kernel(const float* __restrict__ W,
                                                     u16* __restrict__ wbt) {
    __shared__ float tile[64][65];
    const int e  = blockIdx.z;
    const int d0 = blockIdx.y * 64;
    const int f0 = blockIdx.x * 64;
    const int r  = threadIdx.x >> 4;          // 0..15
    const int c4 = (threadIdx.x & 15) * 4;    // 0,4,...,60
    const float* src = W + ((size_t)e << 20) + (size_t)d0 * DH + f0;
    #pragma unroll
    for (int i = 0; i < 4; i++) {
        const int row = i * 16 + r;
        const float4 v = *(const float4*)(src + (size_t)row * DH + c4);
        tile[row][c4]     = v.x;
        tile[row][c4 + 1] = v.y;
        tile[row][c4 + 2] = v.z;
        tile[row][c4 + 3] = v.w;
    }
    __syncthreads();
    u16* dst = wbt + ((size_t)e << 20) + (size_t)f0 * DH + d0;
    #pragma unroll
    for (int i = 0; i < 4; i++) {
        const int orow = i * 16 + r;          // f-index within tile
        ushort4 o;
        o.x = f2b(tile[c4][orow]);
        o.y = f2b(tile[c4 + 1][orow]);
        o.z = f2b(tile[c4 + 2][orow]);
        o.w = f2b(tile[c4 + 3][orow]);
        *(ushort4*)(dst + (size_t)orow * DH + c4) = o;
    }
}

// ---------------- router: logits + softmax + top4 + buckets, fused x->bf16 cast ----------------
__global__ __launch_bounds__(512) void router_kernel(
    const float* __restrict__ x, const float* __restrict__ Wg, const float* __restrict__ bg,
    u16* __restrict__ xb,
    int* __restrict__ bucket_tok, float* __restrict__ bucket_w,
    int* __restrict__ tk_e, float* __restrict__ tk_w,
    int* __restrict__ cnt, float* __restrict__ probsum)
{
    __shared__ int   lcnt[NE];
    __shared__ float lprob[NE];
    __shared__ int   gbase[NE];
    const int tid = threadIdx.x;
    const int wv = tid >> 6, lane = tid & 63;
    const int t = blockIdx.x * 8 + wv;
    if (tid < NE) { lcnt[tid] = 0; lprob[tid] = 0.f; }
    __syncthreads();

    float a[NE] = {};
    {
        const float* xr = x + (size_t)t * DH;
        u16* xbr = xb + (size_t)t * DH;
        #pragma unroll
        for (int it = 0; it < 4; it++) {
            const int d = it * 256 + lane * 4;
            const float4 v = *(const float4*)(xr + d);
            ushort4 o;
            o.x = f2b(v.x); o.y = f2b(v.y); o.z = f2b(v.z); o.w = f2b(v.w);
            *(ushort4*)(xbr + d) = o;
            const float* wr = Wg + d * NE;
            #pragma unroll
            for (int e = 0; e < NE; e++)
                a[e] += v.x * wr[e] + v.y * wr[NE + e] + v.z * wr[2 * NE + e] + v.w * wr[3 * NE + e];
        }
    }
    #pragma unroll
    for (int e = 0; e < NE; e++) {
        float v = a[e];
        #pragma unroll
        for (int off = 32; off > 0; off >>= 1) v += __shfl_down(v, off);
        a[e] = v;
    }

    int idx4[TK]; float w4[TK]; int off4[TK];
    if (lane == 0) {
        float logits[NE], probs[NE];
        float mx = -1e30f;
        #pragma unroll
        for (int e = 0; e < NE; e++) { logits[e] = a[e] + bg[e]; mx = fmaxf(mx, logits[e]); }
        float Z = 0.f;
        #pragma unroll
        for (int e = 0; e < NE; e++) { probs[e] = expf(logits[e] - mx); Z += probs[e]; }
        const float rZ = 1.f / Z;
        #pragma unroll
        for (int e = 0; e < NE; e++) probs[e] *= rZ;

        float rem2[NE];
        #pragma unroll
        for (int e = 0; e < NE; e++) rem2[e] = probs[e];
        float s4 = 0.f;
        #pragma unroll
        for (int k = 0; k < TK; k++) {   // strict > scan from 0 == jax tie-break (lowest idx)
            int best = 0; float bv = rem2[0];
            #pragma unroll
            for (int e = 1; e < NE; e++) if (rem2[e] > bv) { bv = rem2[e]; best = e; }
            idx4[k] = best; w4[k] = bv; s4 += bv; rem2[best] = -1e30f;
        }
        const float rs = 1.f / (s4 + 1e-6f);
        #pragma unroll
        for (int k = 0; k < TK; k++) {
            w4[k] *= rs;
            tk_e[t * TK + k] = idx4[k];
            tk_w[t * TK + k] = w4[k];
            off4[k] = atomicAdd(&lcnt[idx4[k]], 1);
        }
        #pragma unroll
        for (int e = 0; e < NE; e++) atomicAdd(&lprob[e], probs[e]);
    }
    __syncthreads();
    if (tid < NE) {
        gbase[tid] = atomicAdd(&cnt[tid], lcnt[tid]);
        atomicAdd(&probsum[tid], lprob[tid]);
    }
    __syncthreads();
    if (lane == 0) {
        #pragma unroll
        for (int k = 0; k < TK; k++) {
            const int e = idx4[k];
            const int slot = gbase[e] + off4[k];
            bucket_tok[e * T_TOK + slot] = (t << 2) | k;
            bucket_w[e * T_TOK + slot]   = w4[k];
        }
    }
}

// ---------------- grouped gather GEMM: y[t*4+k] = w * (x[t] @ W[e]) ----------------
// m97 structure (BK=32): global_load_lds width-16 staging, unpadded stride-32 LDS, 128x128 tile.
// BK=64 tried (R4): regressed — 16-way frag-read conflicts at 128B row stride + occupancy drop.
__global__ __launch_bounds__(256) void moe_gemm_kernel(
    const u16* __restrict__ xb, const u16* __restrict__ wbt,
    const int* __restrict__ bucket_tok, const float* __restrict__ bucket_w,
    const int* __restrict__ cnt, u16* __restrict__ y)
{
    const int e  = blockIdx.z;
    const int M  = cnt[e];
    const int m0 = blockIdx.y * 128;
    if (m0 >= M) return;
    const int n0 = blockIdx.x * 128;

    __shared__ u16 As[128 * 32];   // unpadded: required by global_load_lds lane layout
    __shared__ u16 Bs[128 * 32];
    __shared__ int   s_tok[128];
    __shared__ float s_w[128];

    const int tid  = threadIdx.x;
    const int lane = tid & 63;
    const int wave = tid >> 6;

    if (tid < 128) {
        const int slot = m0 + tid;
        if (slot < M) {
            s_tok[tid] = bucket_tok[e * T_TOK + slot];
            s_w[tid]   = bucket_w[e * T_TOK + slot];
        } else { s_tok[tid] = -1; s_w[tid] = 0.f; }
    }
    __syncthreads();

    // staging: each wave owns two 16-row segments (1024 B each) of As and Bs.
    // seg s covers rows [16s,16s+16); lane l -> row 16s + l/4, u16 col (l&3)*8.
    const int l4 = lane >> 2;          // 0..15
    const int c8 = (lane & 3) * 8;     // 0,8,16,24
    const int r0 = (2 * wave) * 16 + l4;
    const int r1 = r0 + 16;
    const int t0 = s_tok[r0], t1 = s_tok[r1];
    const u16* gA0 = xb + (size_t)(t0 >= 0 ? (t0 >> 2) : 0) * DH + c8;
    const u16* gA1 = xb + (size_t)(t1 >= 0 ? (t1 >> 2) : 0) * DH + c8;
    const u16* gB0 = wbt + ((size_t)e << 20) + (size_t)(n0 + r0) * DH + c8;
    const u16* gB1 = gB0 + (size_t)16 * DH;
    u16* lA0 = &As[(2 * wave)     * 512];
    u16* lA1 = &As[(2 * wave + 1) * 512];
    u16* lB0 = &Bs[(2 * wave)     * 512];
    u16* lB1 = &Bs[(2 * wave + 1) * 512];

    const int mrow = (wave >> 1) * 64;
    const int ncol = (wave & 1) * 64;
    const int fr   = lane & 15;
    const int fq   = (lane >> 4) * 8;

    f32x4 acc[4][4] = {};

    for (int k0 = 0; k0 < DH; k0 += 32) {
        glds16(gA0 + k0, lA0);
        glds16(gA1 + k0, lA1);
        glds16(gB0 + k0, lB0);
        glds16(gB1 + k0, lB1);
        __syncthreads();
        bf16x8 af[4], bfv[4];
        #pragma unroll
        for (int i = 0; i < 4; i++)
            af[i] = *(const bf16x8*)&As[(mrow + i * 16 + fr) * 32 + fq];
        #pragma unroll
        for (int j = 0; j < 4; j++)
            bfv[j] = *(const bf16x8*)&Bs[(ncol + j * 16 + fr) * 32 + fq];
        #pragma unroll
        for (int i = 0; i < 4; i++)
            #pragma unroll
            for (int j = 0; j < 4; j++)
                acc[i][j] = __builtin_amdgcn_mfma_f32_16x16x32_bf16(af[i], bfv[j], acc[i][j], 0, 0, 0);
        __syncthreads();
    }

    // C/D layout: col = lane&15, row = (lane>>4)*4 + r
    const int cl = lane & 15;
    const int rb = (lane >> 4) * 4;
    #pragma unroll
    for (int i = 0; i < 4; i++) {
        #pragma unroll
        for (int r = 0; r < 4; r++) {
            const int srow = mrow + i * 16 + rb + r;
            const int tok = s_tok[srow];
            if (tok < 0) continue;
            const float w = s_w[srow];
            u16* yr = y + (size_t)tok * DH + (n0 + ncol + cl);
            #pragma unroll
            for (int j = 0; j < 4; j++)
                yr[j * 16] = f2b(acc[i][j][r] * w);
        }
    }
}

// ---------------- combine: out[t] = sum_k y[t*4+k] + sum_k w_k*b[e_k]; block 0 does aux ----------------
__global__ __launch_bounds__(256) void combine_kernel(
    const u16* __restrict__ y, const int* __restrict__ tk_e, const float* __restrict__ tk_w,
    const float* __restrict__ bexp,
    const int* __restrict__ cnt, const float* __restrict__ probsum,
    float* __restrict__ out, float* __restrict__ out_aux)
{
    const int t = blockIdx.x;
    const int c = threadIdx.x * 4;
    if (t == 0 && threadIdx.x == 0) {
        float s = 0.f;
        for (int e = 0; e < NE; e++) s += (float)cnt[e] * probsum[e];
        out_aux[0] = s * (float)NE / ((float)T_TOK * (float)T_TOK);
    }
    float o0 = 0.f, o1 = 0.f, o2 = 0.f, o3 = 0.f;
    #pragma unroll
    for (int k = 0; k < TK; k++) {
        const int e   = tk_e[t * TK + k];
        const float w = tk_w[t * TK + k];
        const ushort4 yv = *(const ushort4*)(y + ((size_t)(t * TK + k)) * DH + c);
        const float4  bv = *(const float4*)(bexp + (size_t)e * DH + c);
        o0 += b2f(yv.x) + w * bv.x;
        o1 += b2f(yv.y) + w * bv.y;
        o2 += b2f(yv.z) + w * bv.z;
        o3 += b2f(yv.w) + w * bv.w;
    }
    float4 ov = {o0, o1, o2, o3};
    *(float4*)(out + (size_t)t * DH + c) = ov;
}

extern "C" void kernel_launch(void* const* d_in, const int* in_sizes, int n_in,
                              void* d_out, int out_size, void* d_ws, size_t ws_size,
                              hipStream_t stream)
{
    const float* x  = (const float*)d_in[0];
    const float* Wg = (const float*)d_in[1];
    const float* bg = (const float*)d_in[2];
    const float* W  = (const float*)d_in[3];
    const float* b  = (const float*)d_in[4];
    float* out = (float*)d_out;

    char* ws = (char*)d_ws;
    u16*   xb         = (u16*)(ws);                    // 16,777,216 B
    u16*   wbt        = (u16*)(ws + 16777216);         // 16,777,216 B
    u16*   y          = (u16*)(ws + 33554432);         // 67,108,864 B
    int*   bucket_tok = (int*)(ws + 100663296);        //    262,144 B
    float* bucket_w   = (float*)(ws + 100925440);      //    262,144 B
    int*   tk_e       = (int*)(ws + 101187584);        //    131,072 B
    float* tk_w       = (float*)(ws + 101318656);      //    131,072 B
    int*   cnt        = (int*)(ws + 101449728);        //         32 B
    float* probsum    = (float*)(ws + 101449760);      //         32 B

    hipMemsetAsync(cnt, 0, 64, stream);  // cnt + probsum

    cast_w_kernel<<<dim3(16, 16, NE), 256, 0, stream>>>(W, wbt);
    router_kernel<<<1024, 512, 0, stream>>>(x, Wg, bg, xb, bucket_tok, bucket_w, tk_e, tk_w, cnt, probsum);
    moe_gemm_kernel<<<dim3(8, 64, NE), 256, 0, stream>>>(xb, wbt, bucket_tok, bucket_w, cnt, y);
    combine_kernel<<<8192, 256, 0, stream>>>(y, tk_e, tk_w, b, cnt, probsum, out, out + (size_t)T_TOK * DH);
}